// Round 13
// baseline (898.149 us; speedup 1.0000x reference)
//
#include <hip/hip_runtime.h>
#include <hip/hip_bf16.h>
#include <math.h>

#define DEVI static __device__ __forceinline__

namespace {
constexpr int Bc   = 2;
constexpr int Nc   = 1024;
constexpr int Dc   = 256;
constexpr int NP1c = 1025;
constexpr int LDZ  = 1028;              // padded fp32 Z row stride
constexpr int LDZB = 1032;              // padded bf16 Z row stride (16B-aligned rows)
constexpr int LDV  = 1028;              // padded u/v stride
constexpr float LN_EPS = 1e-6f;
constexpr float NORMV  = -7.6246189861593985f; // -log(2048)
constexpr float LOGNV  =  6.9314718055994531f; // log(1024)
}

typedef __attribute__((ext_vector_type(8))) short bf16x8;
typedef __attribute__((ext_vector_type(4))) float f32x4;

DEVI void split2(float v, __hip_bfloat16& h, __hip_bfloat16& l) {
    h = __float2bfloat16(v);
    l = __float2bfloat16(v - __bfloat162float(h));
}

DEVI float bf2f(short u) { return __uint_as_float(((unsigned)(unsigned short)u) << 16); }

// async global->LDS, 16B per lane
#define GLDS16(gp, lp) __builtin_amdgcn_global_load_lds( \
    (const __attribute__((address_space(1))) void*)(gp), \
    (__attribute__((address_space(3))) void*)(lp), 16, 0, 0)

// ---------------- helpers ----------------
DEVI float block_sum_256(float v, float* scratch) {
    int t = threadIdx.x;
    scratch[t] = v;
    __syncthreads();
    for (int s = 128; s > 0; s >>= 1) {
        if (t < s) scratch[t] += scratch[t + s];
        __syncthreads();
    }
    float r = scratch[0];
    __syncthreads();
    return r;
}

DEVI void ln_relu_inplace(float* x, const float* g, const float* be, int C, float* scratch) {
    int t = threadIdx.x;
    float v = (t < C) ? x[t] : 0.f;
    float mean = block_sum_256(v, scratch) / (float)C;
    float dv = (t < C) ? (x[t] - mean) : 0.f;
    float var = block_sum_256(dv * dv, scratch) / (float)(C - 1);
    float rstd = 1.f / (sqrtf(var) + LN_EPS);
    if (t < C) x[t] = fmaxf(g[t] * dv * rstd + be[t], 0.f);
    __syncthreads();
}

// ---------------- desc transpose: [dir][b][256][1024] -> descT [(db)*1024+n][256] ----------------
__global__ void transpose_desc(const float* __restrict__ d0, const float* __restrict__ d1,
                               float* __restrict__ dst)
{
    __shared__ float tile[32][33];
    const int db = blockIdx.z, dir = db >> 1, b = db & 1;
    const float* src = dir ? d1 : d0;
    const int n0 = blockIdx.x * 32, c0 = blockIdx.y * 32;
    const int tx = threadIdx.x, ty = threadIdx.y;
    for (int cc = ty; cc < 32; cc += 8)
        tile[cc][tx] = src[((long)b * 256 + c0 + cc) * 1024 + n0 + tx];
    __syncthreads();
    for (int nn = ty; nn < 32; nn += 8)
        dst[((long)db * 1024 + n0 + nn) * 256 + c0 + tx] = tile[tx][nn];
}

// ---------------- keypoint encoder (both dirs; coalesced descT read) ----------------
__global__ __launch_bounds__(256) void kenc_kernel(
    const float* __restrict__ kpts0, const float* __restrict__ kpts1,
    const float* __restrict__ scr0, const float* __restrict__ scr1,
    const float* __restrict__ descT,
    float* __restrict__ descF,
    __hip_bfloat16* __restrict__ catHi, __hip_bfloat16* __restrict__ catLo,
    const float* __restrict__ w0, const float* __restrict__ b0,
    const float* __restrict__ g0, const float* __restrict__ be0,
    const float* __restrict__ w1T, const float* __restrict__ b1,
    const float* __restrict__ g1, const float* __restrict__ be1,
    const float* __restrict__ w2T, const float* __restrict__ b2,
    const float* __restrict__ g2, const float* __restrict__ be2,
    const float* __restrict__ w3T, const float* __restrict__ b3)
{
    __shared__ float xa[256], xb[256], scratch[256];
    const int n = blockIdx.x, db = blockIdx.y, t = threadIdx.x;
    const int dir = db >> 1, b = db & 1;
    const float* kpts = dir ? kpts1 : kpts0;
    const float* scr  = dir ? scr1  : scr0;
    if (t == 0) {
        float kx = kpts[((long)b * Nc + n) * 2 + 0];
        float ky = kpts[((long)b * Nc + n) * 2 + 1];
        xa[0] = (kx - 320.f) * (1.f / 448.f);
        xa[1] = (ky - 240.f) * (1.f / 448.f);
        xa[2] = scr[b * Nc + n];
    }
    __syncthreads();
    if (t < 32) { float a = b0[t]; for (int c = 0; c < 3;  ++c) a += w0[t*3 + c] * xa[c]; xb[t] = a; }
    __syncthreads();
    ln_relu_inplace(xb, g0, be0, 32, scratch);
    if (t < 64) {
        float a = b1[t];
        #pragma unroll 8
        for (int c = 0; c < 32;  ++c) a += w1T[c*64 + t] * xb[c];
        xa[t] = a;
    }
    __syncthreads();
    ln_relu_inplace(xa, g1, be1, 64, scratch);
    if (t < 128) {
        float a = b2[t];
        #pragma unroll 8
        for (int c = 0; c < 64;  ++c) a += w2T[c*128 + t] * xa[c];
        xb[t] = a;
    }
    __syncthreads();
    ln_relu_inplace(xb, g2, be2, 128, scratch);
    {   float a = b3[t];
        #pragma unroll 8
        for (int c = 0; c < 128; ++c) a += w3T[c*256 + t] * xb[c];
        float v = descT[((long)db * Nc + n) * Dc + t] + a;
        descF[((long)db * Nc + n) * Dc + t] = v;
        __hip_bfloat16 h, l; split2(v, h, l);
        long cr = ((long)db * Nc + n) * 512 + t;
        catHi[cr] = h; catLo[cr] = l;
    }
}

__global__ __launch_bounds__(256) void transposeW(
    const float* __restrict__ src, float* __restrict__ dst, int O, int C)
{
    long i = (long)blockIdx.x * 256 + threadIdx.x;
    if (i >= (long)O * C) return;
    int o = (int)(i / C), c = (int)(i % C);
    dst[(long)c * O + o] = src[i];
}

// =======================================================================
// MFMA NT GEMM, BK=32*BKC staged per barrier. A hi(+lo if ALO); B hi(+lo if BLO).
// EPI: 0 fp32 out; 1 bf16 hi/lo planes; 2 qkv -> Q/K/V hi frag-order;
//      3 mlp2 fused resid; 4 bf16 hi only. K % (32*BKC) == 0.
// =======================================================================
template<int BM, int BN, int EPI, int BLO, int ALO, int BKC>
__global__ __launch_bounds__(256) void mfma_nt(
    const short* __restrict__ Ahi0, const short* __restrict__ Alo0, int lda,
    const short* __restrict__ Bhi0, const short* __restrict__ Blo0, int ldb,
    int K, float scale, const float* __restrict__ bias,
    float* __restrict__ outF, __hip_bfloat16* __restrict__ outHi,
    __hip_bfloat16* __restrict__ outLo,
    __hip_bfloat16* __restrict__ outHi2, __hip_bfloat16* __restrict__ outHi3,
    int ldo,
    long aS1, long bS1, long oS1)
{
    constexpr int MI = BM / 32;
    constexpr int NI = BN / 32;
    constexpr int instA = BM / 16, instB = BN / 16;
    constexpr int OFF_AH = 0;
    constexpr int OFF_AL = BM * 32;                       // valid when ALO
    constexpr int OFF_BH = (1 + ALO) * BM * 32;
    constexpr int OFF_BL = OFF_BH + BN * 32;              // valid when BLO
    constexpr int CHUNK = ((1 + ALO) * BM + (1 + BLO) * BN) * 32;
    __shared__ short smem[BKC * CHUNK];

    const int z = blockIdx.z;
    const long aOff = z * aS1, bOff = z * bS1, oOff = z * oS1;
    const short* Ah = Ahi0 + aOff;
    const short* Al = ALO ? (Alo0 + aOff) : nullptr;
    const short* Bh = Bhi0 + bOff;
    const short* Bl = BLO ? (Blo0 + bOff) : nullptr;

    const int m0 = blockIdx.y * BM, n0 = blockIdx.x * BN;
    const int t = threadIdx.x, lane = t & 63, wid = t >> 6;
    const int lr = lane & 15, lg = lane >> 4;
    const int wr = wid >> 1, wc = wid & 1;

    f32x4 acc[MI][NI];
    for (int mi = 0; mi < MI; ++mi)
        for (int ni = 0; ni < NI; ++ni)
            acc[mi][ni] = f32x4{0.f, 0.f, 0.f, 0.f};

    for (int k0 = 0; k0 < K; k0 += 32 * BKC) {
        constexpr int total = (1 + ALO) * instA + (1 + BLO) * instB;
        for (int q = wid; q < total; q += 4) {
            const short* gsrc; int ldg, mi, ploff, row0;
            if (q < instA)                      { gsrc = Ah; ldg = lda; mi = q;          ploff = OFF_AH; row0 = m0; }
            else if (ALO && q < 2 * instA)      { gsrc = Al; ldg = lda; mi = q - instA;  ploff = OFF_AL; row0 = m0; }
            else {
                int rb = q - (1 + ALO) * instA;
                if (rb < instB) { gsrc = Bh; mi = rb;         ploff = OFF_BH; }
                else            { gsrc = Bl; mi = rb - instB; ploff = OFF_BL; }
                ldg = ldb; row0 = n0;
            }
            const short* g = gsrc + (long)(row0 + mi * 16 + lr) * ldg + (k0 + lg * 8);
            #pragma unroll
            for (int c = 0; c < BKC; ++c)
                GLDS16(g + 32 * c, smem + c * CHUNK + ploff + mi * 512);
        }
        __syncthreads();
        #pragma unroll
        for (int kc2 = 0; kc2 < BKC; ++kc2) {
            const short* sm2 = smem + kc2 * CHUNK;
            bf16x8 ah[MI], al[MI];
            #pragma unroll
            for (int mi = 0; mi < MI; ++mi) {
                ah[mi] = *(const bf16x8*)(sm2 + OFF_AH + ((wr * MI + mi) * 64 + lane) * 8);
                if (ALO) al[mi] = *(const bf16x8*)(sm2 + OFF_AL + ((wr * MI + mi) * 64 + lane) * 8);
            }
            #pragma unroll
            for (int ni = 0; ni < NI; ++ni) {
                bf16x8 bh = *(const bf16x8*)(sm2 + OFF_BH + ((wc * NI + ni) * 64 + lane) * 8);
                #pragma unroll
                for (int mi = 0; mi < MI; ++mi) {
                    acc[mi][ni] = __builtin_amdgcn_mfma_f32_16x16x32_bf16(ah[mi], bh, acc[mi][ni], 0, 0, 0);
                    if (ALO) acc[mi][ni] = __builtin_amdgcn_mfma_f32_16x16x32_bf16(al[mi], bh, acc[mi][ni], 0, 0, 0);
                }
                if (BLO) {
                    bf16x8 bl = *(const bf16x8*)(sm2 + OFF_BL + ((wc * NI + ni) * 64 + lane) * 8);
                    #pragma unroll
                    for (int mi = 0; mi < MI; ++mi)
                        acc[mi][ni] = __builtin_amdgcn_mfma_f32_16x16x32_bf16(ah[mi], bl, acc[mi][ni], 0, 0, 0);
                }
            }
        }
        __syncthreads();
    }

    for (int mi = 0; mi < MI; ++mi) {
        for (int i = 0; i < 4; ++i) {
            int row = m0 + wr * (BM / 2) + mi * 16 + lg * 4 + i;
            for (int ni = 0; ni < NI; ++ni) {
                int col = n0 + wc * (BN / 2) + ni * 16 + lr;
                float v = acc[mi][ni][i] * scale;
                if (bias) v += bias[col];
                if (EPI == 0) {
                    outF[(long)row * ldo + col + oOff] = v;
                } else if (EPI == 1) {
                    __hip_bfloat16 h, l;
                    split2(v, h, l);
                    outHi[(long)row * ldo + col + oOff] = h;
                    outLo[(long)row * ldo + col + oOff] = l;
                } else if (EPI == 2) {
                    // Q/K/V hi-only fragment-order scatter
                    int dirb = row >> 10, rloc = row & 1023;
                    int tq = col >> 8, within = col & 255;
                    int h4 = within >> 6, hd = within & 63;
                    __hip_bfloat16 hh = __float2bfloat16(v);
                    if (tq == 2) {
                        int w2 = rloc >> 8, mloc = rloc & 255;
                        int lane2 = ((mloc & 31) >> 3) * 16 + (hd & 15);
                        long idx = ((((long)(dirb*4+h4)*4 + w2)*8 + (mloc>>5))*4 + (hd>>4))*512 + lane2*8 + (mloc&7);
                        outHi2[idx] = hh;
                    } else {
                        int lane2 = ((hd & 31) >> 3) * 16 + (rloc & 15);
                        long idx = (((long)(dirb*4+h4)*64 + (rloc>>4))*2 + (hd>>5))*512 + lane2*8 + (hd&7);
                        if (tq == 0) outHi[idx] = hh;
                        else         outHi3[idx] = hh;
                    }
                } else if (EPI == 3) { // fused residual (descF) + cat planes cols 0..255
                    long i256 = (long)row * 256 + col;
                    v += outF[i256];
                    outF[i256] = v;
                    __hip_bfloat16 h, l;
                    split2(v, h, l);
                    outHi[(long)row * 512 + col] = h;
                    outLo[(long)row * 512 + col] = l;
                } else { // EPI==4: bf16 hi only
                    outHi[(long)row * ldo + col + oOff] = __float2bfloat16(v);
                }
            }
        }
    }
}

// =======================================================================
// Fully fused attention, 32 q-rows per block (K/V reused across 2 row-groups).
// Q,K,V hi-only, fragment-order coalesced loads.
// =======================================================================
__global__ __launch_bounds__(256) void attn_fused(
    const __hip_bfloat16* __restrict__ qFh,
    const __hip_bfloat16* __restrict__ kFh, const __hip_bfloat16* __restrict__ vFh,
    __hip_bfloat16* __restrict__ catHi)
{
    __shared__ short pLds[4 * 32 * 256];   // 64KB; reused as f32 partials
    __shared__ float redm[4][32], reds[4][32];
    const int y = blockIdx.y;
    const int dir = y >> 3, b = (y >> 2) & 1, h = y & 3;
    const int q0 = blockIdx.x * 32;
    const int t = threadIdx.x, lane = t & 63, w = t >> 6;
    const int lr = lane & 15, lg = lane >> 4;
    const int dbQ = dir * 2 + b;
    const int srcdb = (1 - dir) * 2 + b;
    const short* qh = (const short*)qFh;
    const short* kh = (const short*)kFh;
    const short* vh = (const short*)vFh;

    // Q frags for 2 row-groups
    bf16x8 ah[2][2];
    #pragma unroll
    for (int r = 0; r < 2; ++r)
        #pragma unroll
        for (int kc = 0; kc < 2; ++kc) {
            long qb = (((long)(dbQ * 4 + h)) * 64 + (q0 >> 4) + r) * 2 + kc;
            ah[r][kc] = *(const bf16x8*)(qh + qb * 512 + lane * 8);
        }

    f32x4 acc[2][16];
    #pragma unroll
    for (int r = 0; r < 2; ++r)
        #pragma unroll
        for (int ni = 0; ni < 16; ++ni) acc[r][ni] = f32x4{0.f, 0.f, 0.f, 0.f};

    const long kbase0 = (((long)(srcdb * 4 + h)) * 64 + w * 16) * 2;
    #pragma unroll
    for (int ni = 0; ni < 16; ++ni) {
        long kb = (kbase0 + ni * 2) * 512 + lane * 8;
        bf16x8 bh0 = *(const bf16x8*)(kh + kb);
        bf16x8 bh1 = *(const bf16x8*)(kh + kb + 512);
        #pragma unroll
        for (int r = 0; r < 2; ++r) {
            acc[r][ni] = __builtin_amdgcn_mfma_f32_16x16x32_bf16(ah[r][0], bh0, acc[r][ni], 0, 0, 0);
            acc[r][ni] = __builtin_amdgcn_mfma_f32_16x16x32_bf16(ah[r][1], bh1, acc[r][ni], 0, 0, 0);
        }
    }

    // softmax over both row-groups
    float mx[2][4];
    #pragma unroll
    for (int r = 0; r < 2; ++r)
        #pragma unroll
        for (int i = 0; i < 4; ++i) mx[r][i] = -1e30f;
    #pragma unroll
    for (int r = 0; r < 2; ++r)
        #pragma unroll
        for (int ni = 0; ni < 16; ++ni)
            #pragma unroll
            for (int i = 0; i < 4; ++i) {
                float v = acc[r][ni][i] * 0.125f;
                acc[r][ni][i] = v;
                mx[r][i] = fmaxf(mx[r][i], v);
            }
    #pragma unroll
    for (int off = 1; off < 16; off <<= 1)
        #pragma unroll
        for (int r = 0; r < 2; ++r)
            #pragma unroll
            for (int i = 0; i < 4; ++i) mx[r][i] = fmaxf(mx[r][i], __shfl_xor(mx[r][i], off));
    if (lr == 0)
        #pragma unroll
        for (int r = 0; r < 2; ++r)
            #pragma unroll
            for (int i = 0; i < 4; ++i) redm[w][r * 16 + lg * 4 + i] = mx[r][i];
    __syncthreads();
    float Mv[2][4];
    #pragma unroll
    for (int r = 0; r < 2; ++r)
        #pragma unroll
        for (int i = 0; i < 4; ++i) {
            int qq = r * 16 + lg * 4 + i;
            Mv[r][i] = fmaxf(fmaxf(redm[0][qq], redm[1][qq]), fmaxf(redm[2][qq], redm[3][qq]));
        }
    float sm[2][4] = {};
    #pragma unroll
    for (int r = 0; r < 2; ++r)
        #pragma unroll
        for (int ni = 0; ni < 16; ++ni)
            #pragma unroll
            for (int i = 0; i < 4; ++i) {
                float e = __expf(acc[r][ni][i] - Mv[r][i]);
                acc[r][ni][i] = e;
                sm[r][i] += e;
            }
    #pragma unroll
    for (int off = 1; off < 16; off <<= 1)
        #pragma unroll
        for (int r = 0; r < 2; ++r)
            #pragma unroll
            for (int i = 0; i < 4; ++i) sm[r][i] += __shfl_xor(sm[r][i], off);
    if (lr == 0)
        #pragma unroll
        for (int r = 0; r < 2; ++r)
            #pragma unroll
            for (int i = 0; i < 4; ++i) reds[w][r * 16 + lg * 4 + i] = sm[r][i];
    __syncthreads();
    float inv[2][4];
    #pragma unroll
    for (int r = 0; r < 2; ++r)
        #pragma unroll
        for (int i = 0; i < 4; ++i) {
            int qq = r * 16 + lg * 4 + i;
            inv[r][i] = 1.f / (reds[0][qq] + reds[1][qq] + reds[2][qq] + reds[3][qq]);
        }

    // P -> bf16 -> swizzled LDS (wave-private 16KB region; row qq stride 512B)
    char* pB = (char*)pLds + w * 16384;
    #pragma unroll
    for (int r = 0; r < 2; ++r)
        #pragma unroll
        for (int ni = 0; ni < 16; ++ni)
            #pragma unroll
            for (int i = 0; i < 4; ++i) {
                int qq = r * 16 + lg * 4 + i, m = ni * 16 + lr;
                int byte = (qq * 512 + m * 2) ^ ((qq & 7) << 4);
                *(short*)(pB + byte) = (short)__bfloat16_as_ushort(__float2bfloat16(acc[r][ni][i] * inv[r][i]));
            }
    __syncthreads();

    // PV over this wave's m-chunk; V frags reused for both row-groups
    f32x4 acc2[2][4];
    #pragma unroll
    for (int r = 0; r < 2; ++r)
        #pragma unroll
        for (int bi = 0; bi < 4; ++bi) acc2[r][bi] = f32x4{0.f, 0.f, 0.f, 0.f};
    const long vbase0 = (((long)(srcdb * 4 + h)) * 4 + w) * 8;
    #pragma unroll
    for (int km = 0; km < 8; ++km) {
        bf16x8 pa[2];
        #pragma unroll
        for (int r = 0; r < 2; ++r) {
            int rb = ((r * 16 + lr) * 512 + km * 64 + lg * 16) ^ ((lr & 7) << 4);
            pa[r] = *(const bf16x8*)(pB + rb);
        }
        #pragma unroll
        for (int bi = 0; bi < 4; ++bi) {
            long vr = ((vbase0 + km) * 4 + bi) * 512 + lane * 8;
            bf16x8 vhf = *(const bf16x8*)(vh + vr);
            #pragma unroll
            for (int r = 0; r < 2; ++r)
                acc2[r][bi] = __builtin_amdgcn_mfma_f32_16x16x32_bf16(pa[r], vhf, acc2[r][bi], 0, 0, 0);
        }
    }
    __syncthreads();
    float* pr = (float*)pLds;   // [w][32 q][64 d]
    #pragma unroll
    for (int r = 0; r < 2; ++r)
        #pragma unroll
        for (int bi = 0; bi < 4; ++bi)
            #pragma unroll
            for (int i = 0; i < 4; ++i)
                pr[w * 2048 + (r * 16 + lg * 4 + i) * 64 + bi * 16 + lr] = acc2[r][bi][i];
    __syncthreads();
    #pragma unroll
    for (int k = 0; k < 8; ++k) {
        int e = t + k * 256;
        float v = pr[e] + pr[2048 + e] + pr[4096 + e] + pr[6144 + e];
        int qq = e >> 6, d = e & 63;
        long a = ((long)dbQ * 1024 + q0 + qq) * 512 + 256 + h * 64 + d;
        catHi[a] = __float2bfloat16(v);
    }
}

// ---------------- LN(channel,ddof=1,eps-on-std)+ReLU; wave-per-row; bf16 in-place ----------------
__global__ __launch_bounds__(256) void ln_relu_w(
    __hip_bfloat16* __restrict__ y, const float* __restrict__ g, const float* __restrict__ be)
{
    const int t = threadIdx.x, lane = t & 63, w = t >> 6;
    const long row = (long)blockIdx.x * 4 + w;
    short* src = (short*)y + row * 512;
    bf16x8 r = *(const bf16x8*)(src + lane * 8);
    float xv[8];
    #pragma unroll
    for (int k = 0; k < 8; ++k) xv[k] = bf2f(r[k]);
    float s = 0.f, q = 0.f;
    #pragma unroll
    for (int k = 0; k < 8; ++k) { s += xv[k]; q += xv[k] * xv[k]; }
    #pragma unroll
    for (int off = 1; off < 64; off <<= 1) {
        s += __shfl_xor(s, off);
        q += __shfl_xor(q, off);
    }
    float mean = s / 512.f;
    float var = fmaxf((q - 512.f * mean * mean) / 511.f, 0.f);
    float rstd = 1.f / (sqrtf(var) + LN_EPS);
    float4 g0 = ((const float4*)g)[lane * 2], g1 = ((const float4*)g)[lane * 2 + 1];
    float4 b0 = ((const float4*)be)[lane * 2], b1 = ((const float4*)be)[lane * 2 + 1];
    float gv[8] = {g0.x, g0.y, g0.z, g0.w, g1.x, g1.y, g1.z, g1.w};
    float bv[8] = {b0.x, b0.y, b0.z, b0.w, b1.x, b1.y, b1.z, b1.w};
    bf16x8 outv;
    #pragma unroll
    for (int k = 0; k < 8; ++k) {
        float o = fmaxf(gv[k] * (xv[k] - mean) * rstd + bv[k], 0.f);
        outv[k] = (short)__bfloat16_as_ushort(__float2bfloat16(o));
    }
    *(bf16x8*)(src + lane * 8) = outv;
}

// ---------------- weight converts ----------------
__global__ __launch_bounds__(256) void wconv_hi(
    const float* __restrict__ w, __hip_bfloat16* __restrict__ hi, long total)
{
    long i = (long)blockIdx.x * 256 + threadIdx.x;
    if (i >= total) return;
    hi[i] = __float2bfloat16(w[i]);
}

__global__ __launch_bounds__(256) void wconv_proj(
    const float* __restrict__ w, __hip_bfloat16* __restrict__ hi)
{
    long i = (long)blockIdx.x * 256 + threadIdx.x;
    if (i >= 9L * 768 * 256) return;
    long l9 = i / (768 * 256);
    int rem = (int)(i % (768 * 256));
    int op = rem / 256, c = rem % 256;
    int tq = op / 256, within = op % 256;
    int h = within / 64, hd = within % 64;
    int o = tq * 256 + hd * 4 + h;
    hi[i] = __float2bfloat16(w[(l9 * 768 + o) * 256 + c]);
}

__global__ void wconv_proj_bias(const float* __restrict__ b, float* __restrict__ bp)
{
    int i = blockIdx.x * 256 + threadIdx.x;
    if (i >= 9 * 768) return;
    int l9 = i / 768, op = i % 768;
    int tq = op / 256, within = op % 256;
    int h = within / 64, hd = within % 64;
    bp[i] = b[(l9 * 3 + tq) * 256 + hd * 4 + h];
}

// WmT planes: [l][c=h*64+hd][j] = Wm[l][j][hd*4+h]  (hi/lo: B operand of fold GEMM)
__global__ __launch_bounds__(256) void wconv_mergeT(
    const float* __restrict__ w, __hip_bfloat16* __restrict__ hi, __hip_bfloat16* __restrict__ lo)
{
    long i = (long)blockIdx.x * 256 + threadIdx.x;
    if (i >= 9L * 256 * 256) return;
    long l9 = i / (256 * 256);
    int rem = (int)(i % (256 * 256));
    int c = rem / 256, j = rem % 256;
    int h = c / 64, hd = c % 64;
    float v = w[(l9 * 256 + j) * 256 + (hd * 4 + h)];
    __hip_bfloat16 hh, ll; split2(v, hh, ll);
    hi[i] = hh; lo[i] = ll;
}

// mlp1 W split: cols 0..255 -> m1cHi[..512-wide]; cols 256..511 -> m1b hi/lo [..256-wide]
__global__ __launch_bounds__(256) void wconv_m1(
    const float* __restrict__ w,
    __hip_bfloat16* __restrict__ m1cHi,
    __hip_bfloat16* __restrict__ m1bHi, __hip_bfloat16* __restrict__ m1bLo)
{
    long i = (long)blockIdx.x * 256 + threadIdx.x;
    if (i >= 9L * 512 * 512) return;
    long lo9 = i / 512;
    int c = (int)(i % 512);
    if (c < 256) {
        m1cHi[lo9 * 512 + c] = __float2bfloat16(w[i]);
    } else {
        __hip_bfloat16 hh, ll; split2(w[i], hh, ll);
        m1bHi[lo9 * 256 + c - 256] = hh; m1bLo[lo9 * 256 + c - 256] = ll;
    }
}

// b1c[l*512+o] = b1[l][o] + sum_j W1[l][o][256+j]*bm[l][j]
__global__ __launch_bounds__(64) void bias_fold(
    const float* __restrict__ w1, const float* __restrict__ b1,
    const float* __restrict__ bm, float* __restrict__ out)
{
    int og = blockIdx.x;
    int l = og >> 9, o = og & 511;
    int t = threadIdx.x;
    float s = 0.f;
    for (int j = t; j < 256; j += 64)
        s += w1[((long)l * 512 + o) * 512 + 256 + j] * bm[l * 256 + j];
    for (int off = 32; off > 0; off >>= 1) s += __shfl_down(s, off);
    if (t == 0) out[og] = b1[(long)l * 512 + o] + s;
}

// ---------------- Sinkhorn pieces ----------------
__global__ void bins_fill(float* __restrict__ Z, const float* __restrict__ alpha_p)
{
    float alpha = alpha_p[0];
    int idx = blockIdx.x * 256 + threadIdx.x;
    int b = blockIdx.y;
    float* Zb = Z + (long)b * NP1c * LDZ;
    if (idx < NP1c) Zb[(long)1024 * LDZ + idx] = alpha;
    else { int i = idx - NP1c; if (i < 1024) Zb[(long)i * LDZ + 1024] = alpha; }
}

// fp32 Zm -> bf16 straight (Zb) + bf16 transposed (ZTb)
__global__ void transpose_convert(const float* __restrict__ Z,
                                  __hip_bfloat16* __restrict__ Zb,
                                  __hip_bfloat16* __restrict__ ZTb)
{
    __shared__ float tile[32][33];
    int b = blockIdx.z;
    int i0 = blockIdx.y * 32, j0 = blockIdx.x * 32;
    int tx = threadIdx.x, ty = threadIdx.y;
    const float* Zs = Z + (long)b * NP1c * LDZ;
    for (int ii = ty; ii < 32; ii += 8) {
        int i = i0 + ii, j = j0 + tx;
        if (i < NP1c && j < NP1c) {
            float v = Zs[(long)i * LDZ + j];
            tile[ii][tx] = v;
            Zb[((long)b * NP1c + i) * LDZB + j] = __float2bfloat16(v);
        }
    }
    __syncthreads();
    for (int jj = ty; jj < 32; jj += 8) {
        int j = j0 + jj, i = i0 + tx;
        if (j < NP1c && i < NP1c)
            ZTb[((long)b * NP1c + j) * LDZB + i] = __float2bfloat16(tile[tx][jj]);
    }
}

__global__ void zero_vec2(float* __restrict__ a, float* __restrict__ b, int n)
{
    int i = blockIdx.x * 256 + threadIdx.x;
    if (i < n) { a[i] = 0.f; b[i] = 0.f; }
}

// wave-per-row LSE on bf16 M: out[b][i] = lmu(i) - LSE_j( M[b][i][j] + addv[b][j] )
__global__ __launch_bounds__(256) void sinkhorn_lse_bf(
    const __hip_bfloat16* __restrict__ M, const float* __restrict__ addv, float* __restrict__ outv)
{
    const int t = threadIdx.x, lane = t & 63, w = t >> 6;
    long rowid = (long)blockIdx.x * 4 + w;
    if (rowid >= 2 * NP1c) return;        // wave-uniform exit
    int b = rowid >= NP1c ? 1 : 0;
    int i = (int)(rowid - (long)b * NP1c);
    const short* row = (const short*)M + ((long)b * NP1c + i) * LDZB;
    const float* av = addv + (long)b * LDV;
    bf16x8 x0 = *(const bf16x8*)(row + lane * 16);
    bf16x8 x1 = *(const bf16x8*)(row + lane * 16 + 8);
    float u[16];
    #pragma unroll
    for (int k = 0; k < 4; ++k) {
        float4 a = ((const float4*)av)[lane * 4 + k];
        int e = k * 4;
        u[e+0] = ((e+0 < 8) ? bf2f(x0[e+0]) : bf2f(x1[e-8+0])) + a.x;
        u[e+1] = ((e+1 < 8) ? bf2f(x0[e+1]) : bf2f(x1[e-8+1])) + a.y;
        u[e+2] = ((e+2 < 8) ? bf2f(x0[e+2]) : bf2f(x1[e-8+2])) + a.z;
        u[e+3] = ((e+3 < 8) ? bf2f(x0[e+3]) : bf2f(x1[e-8+3])) + a.w;
    }
    float m = -1e30f;
    #pragma unroll
    for (int k = 0; k < 16; ++k) m = fmaxf(m, u[k]);
    float s = 0.f;
    #pragma unroll
    for (int k = 0; k < 16; ++k) s += __expf(u[k] - m);
    if (lane == 0) {
        float v4 = bf2f(row[1024]) + av[1024];
        if (v4 > m) { s = s * __expf(m - v4) + 1.f; m = v4; }
        else        { s += __expf(v4 - m); }
    }
    #pragma unroll
    for (int off = 1; off < 64; off <<= 1) {
        float m2 = __shfl_xor(m, off);
        float s2 = __shfl_xor(s, off);
        float mm = fmaxf(m, m2);
        s = s * __expf(m - mm) + s2 * __expf(m2 - mm);
        m = mm;
    }
    if (lane == 0) {
        float lse = m + __logf(s);
        float lmu = (i < 1024) ? NORMV : (LOGNV + NORMV);
        outv[(long)b * LDV + i] = lmu - lse;
    }
}

__global__ __launch_bounds__(256) void final_out_k(
    const float* __restrict__ Z, const float* __restrict__ u,
    const float* __restrict__ v, float* __restrict__ outp)
{
    const int i = blockIdx.x, b = blockIdx.y, t = threadIdx.x;
    const float* row = Z + ((long)b * NP1c + i) * LDZ;
    float* orow = outp + ((long)b * NP1c + i) * NP1c;
    float ui = u[(long)b * LDV + i];
    for (int j = t; j < NP1c; j += 256)
        orow[j] = row[j] + ui + v[(long)b * LDV + j] - NORMV;
}

// =======================================================================
extern "C" void kernel_launch(void* const* d_in, const int* in_sizes, int n_in,
                              void* d_out, int out_size, void* d_ws, size_t ws_size,
                              hipStream_t stream)
{
    (void)in_sizes; (void)n_in; (void)out_size; (void)ws_size;
    const float* kpts0   = (const float*)d_in[0];
    const float* kpts1   = (const float*)d_in[1];
    const float* scores0 = (const float*)d_in[2];
    const float* scores1 = (const float*)d_in[3];
    const float* desc0   = (const float*)d_in[4];
    const float* desc1   = (const float*)d_in[5];
    const float* kw0 = (const float*)d_in[6];  const float* kb0 = (const float*)d_in[7];
    const float* kg0 = (const float*)d_in[8];  const float* ke0 = (const float*)d_in[9];
    const float* kw1 = (const float*)d_in[10]; const float* kb1 = (const float*)d_in[11];
    const float* kg1 = (const float*)d_in[12]; const float* ke1 = (const float*)d_in[13];
    const float* kw2 = (const float*)d_in[14]; const float* kb2 = (const float*)d_in[15];
    const float* kg2 = (const float*)d_in[16]; const float* ke2 = (const float*)d_in[17];
    const float* kw3 = (const float*)d_in[18]; const float* kb3 = (const float*)d_in[19];
    const float* gnn_proj_w  = (const float*)d_in[20];
    const float* gnn_proj_b  = (const float*)d_in[21];
    const float* gnn_merge_w = (const float*)d_in[22];
    const float* gnn_merge_b = (const float*)d_in[23];
    const float* gnn_mlp1_w  = (const float*)d_in[24];
    const float* gnn_mlp1_b  = (const float*)d_in[25];
    const float* gnn_ln_g    = (const float*)d_in[26];
    const float* gnn_ln_b    = (const float*)d_in[27];
    const float* gnn_mlp2_w  = (const float*)d_in[28];
    const float* gnn_mlp2_b  = (const float*)d_in[29];
    const float* final_w     = (const float*)d_in[30];
    const float* final_b     = (const float*)d_in[31];
    const float* bin_score   = (const float*)d_in[32];

    char* wsb = (char*)d_ws;
    size_t off = 0;
    auto alloc = [&](size_t bytes) -> void* {
        void* p = wsb + off;
        off = (off + bytes + 255) & ~(size_t)255;
        return p;
    };
    typedef __hip_bfloat16 bf;
    const long ROWS = 4L * Nc;
    // fp32
    float* descF  = (float*)alloc(ROWS * 256 * 4);
    float* descT  = (float*)alloc(ROWS * 256 * 4);
    float* Zm     = (float*)alloc((long)Bc * NP1c * LDZ * 4);
    float* uvec   = (float*)alloc(Bc * LDV * 4);
    float* vvec   = (float*)alloc(Bc * LDV * 4);
    float* projBp = (float*)alloc(9L * 768 * 4);
    float* b1c    = (float*)alloc(9L * 512 * 4);
    float* kw1T   = (float*)alloc(32L * 64 * 4);
    float* kw2T   = (float*)alloc(64L * 128 * 4);
    float* kw3T   = (float*)alloc(128L * 256 * 4);
    // bf16 Z copies for Sinkhorn iterations
    bf* Zb  = (bf*)alloc((long)Bc * NP1c * LDZB * 2);
    bf* ZTb = (bf*)alloc((long)Bc * NP1c * LDZB * 2);
    // activation planes
    bf* catHi = (bf*)alloc(ROWS * 512 * 2);  bf* catLo = (bf*)alloc(ROWS * 512 * 2);
    bf* qFh = (bf*)alloc(1048576 * 2);
    bf* kFh = (bf*)alloc(1048576 * 2);
    bf* vFh = (bf*)alloc(1048576 * 2);
    bf* ybHi  = (bf*)alloc(ROWS * 512 * 2);
    bf* mdHi  = (bf*)alloc(ROWS * 256 * 2);  bf* mdLo  = (bf*)alloc(ROWS * 256 * 2);
    // weight planes
    bf* projHi = (bf*)alloc(9L*768*256*2);
    bf* mrgTHi = (bf*)alloc(9L*256*256*2);   bf* mrgTLo = (bf*)alloc(9L*256*256*2);
    bf* m1bHi  = (bf*)alloc(9L*512*256*2);   bf* m1bLo  = (bf*)alloc(9L*512*256*2);
    bf* m1cHi  = (bf*)alloc(9L*512*512*2);
    bf* m2Hi   = (bf*)alloc(9L*256*512*2);
    bf* finHi  = (bf*)alloc(256L*256*2);

    // ---- weight prep ----
    wconv_proj<<<dim3((9*768*256+255)/256), 256, 0, stream>>>(gnn_proj_w, projHi);
    wconv_proj_bias<<<dim3(27), 256, 0, stream>>>(gnn_proj_b, projBp);
    wconv_mergeT<<<dim3((9*256*256+255)/256), 256, 0, stream>>>(gnn_merge_w, mrgTHi, mrgTLo);
    wconv_m1<<<dim3((int)((9L*512*512+255)/256)), 256, 0, stream>>>(gnn_mlp1_w, m1cHi, m1bHi, m1bLo);
    wconv_hi<<<dim3((9*256*512+255)/256), 256, 0, stream>>>(gnn_mlp2_w, m2Hi, 9L*256*512);
    wconv_hi<<<dim3((256*256+255)/256), 256, 0, stream>>>(final_w, finHi, 256L*256);
    bias_fold<<<dim3(9*512), 64, 0, stream>>>(gnn_mlp1_w, gnn_mlp1_b, gnn_merge_b, b1c);
    transposeW<<<dim3((64*32+255)/256), 256, 0, stream>>>(kw1, kw1T, 64, 32);
    transposeW<<<dim3((128*64+255)/256), 256, 0, stream>>>(kw2, kw2T, 128, 64);
    transposeW<<<dim3((256*128+255)/256), 256, 0, stream>>>(kw3, kw3T, 256, 128);
    // combined mlp1 cols 256..511 = W1b x WmT^T per layer (hi out; inputs hi/lo)
    mfma_nt<128,128,4,1,1,2><<<dim3(2,4,9), 256, 0, stream>>>(
        (const short*)m1bHi, (const short*)m1bLo, 256,
        (const short*)mrgTHi, (const short*)mrgTLo, 256,
        256, 1.f, nullptr,
        nullptr, m1cHi + 256, nullptr, nullptr, nullptr, 512,
        512L*256, 256L*256, 512L*512);

    // ---- desc transpose + keypoint encoder -> descF + cat planes cols 0..255 ----
    transpose_desc<<<dim3(32,8,4), dim3(32,8), 0, stream>>>(desc0, desc1, descT);
    kenc_kernel<<<dim3(Nc, 4), 256, 0, stream>>>(
        kpts0, kpts1, scores0, scores1, descT, descF, catHi, catLo,
        kw0, kb0, kg0, ke0, kw1T, kb1, kg1, ke1, kw2T, kb2, kg2, ke2, kw3T, kb3);

    // ---- GNN layers ----
    for (int l = 0; l < 9; ++l) {
        // 1) qkv GEMM (A hi, W hi, BKC=4) -> Q/K/V hi fragment-order
        mfma_nt<64,64,2,0,0,4><<<dim3(12,64,1), 256, 0, stream>>>(
            (const short*)catHi, nullptr, 512,
            (const short*)(projHi + (long)l*768*256), nullptr, 256,
            256, 1.f, projBp + (long)l*768,
            nullptr, qFh, nullptr, vFh, kFh, 0,
            0, 0, 0);
        // 2) fused attention (32 q-rows/block) -> catbuf hi cols 256..511
        attn_fused<<<dim3(32, 16), 256, 0, stream>>>(qFh, kFh, vFh, catHi);
        // 3) mlp1 (A hi, W hi, BKC=4) -> ybHi bf16 directly
        mfma_nt<64,64,4,0,0,4><<<dim3(8,64,1), 256, 0, stream>>>(
            (const short*)catHi, nullptr, 512,
            (const short*)(m1cHi + (long)l*512*512), nullptr, 512,
            512, 1.f, b1c + (long)l*512,
            nullptr, ybHi, nullptr, nullptr, nullptr, 512,
            0, 0, 0);
        // 4) LN+ReLU (wave-per-row, bf16 in-place)
        ln_relu_w<<<dim3(1024), 256, 0, stream>>>(
            ybHi, gnn_ln_g + (long)l*512, gnn_ln_b + (long)l*512);
        // 5) mlp2 (A hi, W hi, BKC=4) fused residual -> descF + cat hi/lo cols 0..255
        mfma_nt<64,64,3,0,0,4><<<dim3(4,64,1), 256, 0, stream>>>(
            (const short*)ybHi, nullptr, 512,
            (const short*)(m2Hi + (long)l*256*512), nullptr, 512,
            512, 1.f, gnn_mlp2_b + (long)l*256,
            descF, catHi, catLo, nullptr, nullptr, 0,
            0, 0, 0);
    }

    // ---- final projection (A hi/lo, W hi, BKC=4) -> mdesc planes ----
    mfma_nt<64,64,1,0,1,4><<<dim3(4,64,1), 256, 0, stream>>>(
        (const short*)catHi, (const short*)catLo, 512,
        (const short*)finHi, nullptr, 256,
        256, 1.f, final_b,
        nullptr, mdHi, mdLo, nullptr, nullptr, 256,
        0, 0, 0);
    // ---- score matrix into Z (activation x activation: full hi/lo; BKC=4) ----
    mfma_nt<64,64,0,1,1,4><<<dim3(16,16,2), 256, 0, stream>>>(
        (const short*)mdHi, (const short*)mdLo, 256,
        (const short*)mdHi + 2048L*256, (const short*)mdLo + 2048L*256, 256,
        256, 1.f/16.f, nullptr,
        Zm, nullptr, nullptr, nullptr, nullptr, LDZ,
        1024L*256, 1024L*256, (long)NP1c*LDZ);
    bins_fill<<<dim3(9,2), 256, 0, stream>>>(Zm, bin_score);

    // ---- Sinkhorn: bf16 copies, 20 iterations (wave-per-row LSE) ----
    transpose_convert<<<dim3(33,33,2), dim3(32,8), 0, stream>>>(Zm, Zb, ZTb);
    zero_vec2<<<dim3((2*LDV+255)/256), 256, 0, stream>>>(uvec, vvec, Bc * LDV);
    for (int it = 0; it < 20; ++it) {
        sinkhorn_lse_bf<<<dim3(513), 256, 0, stream>>>(Zb,  vvec, uvec);
        sinkhorn_lse_bf<<<dim3(513), 256, 0, stream>>>(ZTb, uvec, vvec);
    }
    final_out_k<<<dim3(NP1c, Bc), 256, 0, stream>>>(Zm, uvec, vvec, (float*)d_out);
}

// Round 14
// 878.352 us; speedup vs baseline: 1.0225x; 1.0225x over previous
//
#include <hip/hip_runtime.h>
#include <hip/hip_bf16.h>
#include <math.h>

#define DEVI static __device__ __forceinline__

namespace {
constexpr int Bc   = 2;
constexpr int Nc   = 1024;
constexpr int Dc   = 256;
constexpr int NP1c = 1025;
constexpr int LDZ  = 1028;              // padded Z row stride (16B-aligned)
constexpr int LDV  = 1028;              // padded u/v stride
constexpr float LN_EPS = 1e-6f;
constexpr float NORMV  = -7.6246189861593985f; // -log(2048)
constexpr float LOGNV  =  6.9314718055994531f; // log(1024)
}

typedef __attribute__((ext_vector_type(8))) short bf16x8;
typedef __attribute__((ext_vector_type(4))) float f32x4;

DEVI void split2(float v, __hip_bfloat16& h, __hip_bfloat16& l) {
    h = __float2bfloat16(v);
    l = __float2bfloat16(v - __bfloat162float(h));
}

DEVI float bf2f(short u) { return __uint_as_float(((unsigned)(unsigned short)u) << 16); }

// async global->LDS, 16B per lane
#define GLDS16(gp, lp) __builtin_amdgcn_global_load_lds( \
    (const __attribute__((address_space(1))) void*)(gp), \
    (__attribute__((address_space(3))) void*)(lp), 16, 0, 0)

// ---------------- helpers ----------------
DEVI float block_sum_256(float v, float* scratch) {
    int t = threadIdx.x;
    scratch[t] = v;
    __syncthreads();
    for (int s = 128; s > 0; s >>= 1) {
        if (t < s) scratch[t] += scratch[t + s];
        __syncthreads();
    }
    float r = scratch[0];
    __syncthreads();
    return r;
}

DEVI void ln_relu_inplace(float* x, const float* g, const float* be, int C, float* scratch) {
    int t = threadIdx.x;
    float v = (t < C) ? x[t] : 0.f;
    float mean = block_sum_256(v, scratch) / (float)C;
    float dv = (t < C) ? (x[t] - mean) : 0.f;
    float var = block_sum_256(dv * dv, scratch) / (float)(C - 1);
    float rstd = 1.f / (sqrtf(var) + LN_EPS);
    if (t < C) x[t] = fmaxf(g[t] * dv * rstd + be[t], 0.f);
    __syncthreads();
}

// ---------------- desc transpose: [dir][b][256][1024] -> descT [(db)*1024+n][256] ----------------
__global__ void transpose_desc(const float* __restrict__ d0, const float* __restrict__ d1,
                               float* __restrict__ dst)
{
    __shared__ float tile[32][33];
    const int db = blockIdx.z, dir = db >> 1, b = db & 1;
    const float* src = dir ? d1 : d0;
    const int n0 = blockIdx.x * 32, c0 = blockIdx.y * 32;
    const int tx = threadIdx.x, ty = threadIdx.y;
    for (int cc = ty; cc < 32; cc += 8)
        tile[cc][tx] = src[((long)b * 256 + c0 + cc) * 1024 + n0 + tx];
    __syncthreads();
    for (int nn = ty; nn < 32; nn += 8)
        dst[((long)db * 1024 + n0 + nn) * 256 + c0 + tx] = tile[tx][nn];
}

// ---------------- keypoint encoder (both dirs; coalesced descT read) ----------------
__global__ __launch_bounds__(256) void kenc_kernel(
    const float* __restrict__ kpts0, const float* __restrict__ kpts1,
    const float* __restrict__ scr0, const float* __restrict__ scr1,
    const float* __restrict__ descT,
    float* __restrict__ descF,
    __hip_bfloat16* __restrict__ catHi, __hip_bfloat16* __restrict__ catLo,
    const float* __restrict__ w0, const float* __restrict__ b0,
    const float* __restrict__ g0, const float* __restrict__ be0,
    const float* __restrict__ w1T, const float* __restrict__ b1,
    const float* __restrict__ g1, const float* __restrict__ be1,
    const float* __restrict__ w2T, const float* __restrict__ b2,
    const float* __restrict__ g2, const float* __restrict__ be2,
    const float* __restrict__ w3T, const float* __restrict__ b3)
{
    __shared__ float xa[256], xb[256], scratch[256];
    const int n = blockIdx.x, db = blockIdx.y, t = threadIdx.x;
    const int dir = db >> 1, b = db & 1;
    const float* kpts = dir ? kpts1 : kpts0;
    const float* scr  = dir ? scr1  : scr0;
    if (t == 0) {
        float kx = kpts[((long)b * Nc + n) * 2 + 0];
        float ky = kpts[((long)b * Nc + n) * 2 + 1];
        xa[0] = (kx - 320.f) * (1.f / 448.f);
        xa[1] = (ky - 240.f) * (1.f / 448.f);
        xa[2] = scr[b * Nc + n];
    }
    __syncthreads();
    if (t < 32) { float a = b0[t]; for (int c = 0; c < 3;  ++c) a += w0[t*3 + c] * xa[c]; xb[t] = a; }
    __syncthreads();
    ln_relu_inplace(xb, g0, be0, 32, scratch);
    if (t < 64) {
        float a = b1[t];
        #pragma unroll 8
        for (int c = 0; c < 32;  ++c) a += w1T[c*64 + t] * xb[c];
        xa[t] = a;
    }
    __syncthreads();
    ln_relu_inplace(xa, g1, be1, 64, scratch);
    if (t < 128) {
        float a = b2[t];
        #pragma unroll 8
        for (int c = 0; c < 64;  ++c) a += w2T[c*128 + t] * xa[c];
        xb[t] = a;
    }
    __syncthreads();
    ln_relu_inplace(xb, g2, be2, 128, scratch);
    {   float a = b3[t];
        #pragma unroll 8
        for (int c = 0; c < 128; ++c) a += w3T[c*256 + t] * xb[c];
        float v = descT[((long)db * Nc + n) * Dc + t] + a;
        descF[((long)db * Nc + n) * Dc + t] = v;
        __hip_bfloat16 h, l; split2(v, h, l);
        long cr = ((long)db * Nc + n) * 512 + t;
        catHi[cr] = h; catLo[cr] = l;
    }
}

__global__ __launch_bounds__(256) void transposeW(
    const float* __restrict__ src, float* __restrict__ dst, int O, int C)
{
    long i = (long)blockIdx.x * 256 + threadIdx.x;
    if (i >= (long)O * C) return;
    int o = (int)(i / C), c = (int)(i % C);
    dst[(long)c * O + o] = src[i];
}

// =======================================================================
// MFMA NT GEMM, BK=32*BKC staged per barrier. A hi(+lo if ALO); B hi(+lo if BLO).
// EPI: 0 fp32 out; 1 bf16 hi/lo planes; 2 qkv -> Q/K/V hi frag-order;
//      3 mlp2 fused resid; 4 bf16 hi only. K % (32*BKC) == 0.
// =======================================================================
template<int BM, int BN, int EPI, int BLO, int ALO, int BKC>
__global__ __launch_bounds__(256) void mfma_nt(
    const short* __restrict__ Ahi0, const short* __restrict__ Alo0, int lda,
    const short* __restrict__ Bhi0, const short* __restrict__ Blo0, int ldb,
    int K, float scale, const float* __restrict__ bias,
    float* __restrict__ outF, __hip_bfloat16* __restrict__ outHi,
    __hip_bfloat16* __restrict__ outLo,
    __hip_bfloat16* __restrict__ outHi2, __hip_bfloat16* __restrict__ outHi3,
    int ldo,
    long aS1, long bS1, long oS1)
{
    constexpr int MI = BM / 32;
    constexpr int NI = BN / 32;
    constexpr int instA = BM / 16, instB = BN / 16;
    constexpr int OFF_AH = 0;
    constexpr int OFF_AL = BM * 32;                       // valid when ALO
    constexpr int OFF_BH = (1 + ALO) * BM * 32;
    constexpr int OFF_BL = OFF_BH + BN * 32;              // valid when BLO
    constexpr int CHUNK = ((1 + ALO) * BM + (1 + BLO) * BN) * 32;
    __shared__ short smem[BKC * CHUNK];

    const int z = blockIdx.z;
    const long aOff = z * aS1, bOff = z * bS1, oOff = z * oS1;
    const short* Ah = Ahi0 + aOff;
    const short* Al = ALO ? (Alo0 + aOff) : nullptr;
    const short* Bh = Bhi0 + bOff;
    const short* Bl = BLO ? (Blo0 + bOff) : nullptr;

    const int m0 = blockIdx.y * BM, n0 = blockIdx.x * BN;
    const int t = threadIdx.x, lane = t & 63, wid = t >> 6;
    const int lr = lane & 15, lg = lane >> 4;
    const int wr = wid >> 1, wc = wid & 1;

    f32x4 acc[MI][NI];
    for (int mi = 0; mi < MI; ++mi)
        for (int ni = 0; ni < NI; ++ni)
            acc[mi][ni] = f32x4{0.f, 0.f, 0.f, 0.f};

    for (int k0 = 0; k0 < K; k0 += 32 * BKC) {
        constexpr int total = (1 + ALO) * instA + (1 + BLO) * instB;
        for (int q = wid; q < total; q += 4) {
            const short* gsrc; int ldg, mi, ploff, row0;
            if (q < instA)                      { gsrc = Ah; ldg = lda; mi = q;          ploff = OFF_AH; row0 = m0; }
            else if (ALO && q < 2 * instA)      { gsrc = Al; ldg = lda; mi = q - instA;  ploff = OFF_AL; row0 = m0; }
            else {
                int rb = q - (1 + ALO) * instA;
                if (rb < instB) { gsrc = Bh; mi = rb;         ploff = OFF_BH; }
                else            { gsrc = Bl; mi = rb - instB; ploff = OFF_BL; }
                ldg = ldb; row0 = n0;
            }
            const short* g = gsrc + (long)(row0 + mi * 16 + lr) * ldg + (k0 + lg * 8);
            #pragma unroll
            for (int c = 0; c < BKC; ++c)
                GLDS16(g + 32 * c, smem + c * CHUNK + ploff + mi * 512);
        }
        __syncthreads();
        #pragma unroll
        for (int kc2 = 0; kc2 < BKC; ++kc2) {
            const short* sm2 = smem + kc2 * CHUNK;
            bf16x8 ah[MI], al[MI];
            #pragma unroll
            for (int mi = 0; mi < MI; ++mi) {
                ah[mi] = *(const bf16x8*)(sm2 + OFF_AH + ((wr * MI + mi) * 64 + lane) * 8);
                if (ALO) al[mi] = *(const bf16x8*)(sm2 + OFF_AL + ((wr * MI + mi) * 64 + lane) * 8);
            }
            #pragma unroll
            for (int ni = 0; ni < NI; ++ni) {
                bf16x8 bh = *(const bf16x8*)(sm2 + OFF_BH + ((wc * NI + ni) * 64 + lane) * 8);
                #pragma unroll
                for (int mi = 0; mi < MI; ++mi) {
                    acc[mi][ni] = __builtin_amdgcn_mfma_f32_16x16x32_bf16(ah[mi], bh, acc[mi][ni], 0, 0, 0);
                    if (ALO) acc[mi][ni] = __builtin_amdgcn_mfma_f32_16x16x32_bf16(al[mi], bh, acc[mi][ni], 0, 0, 0);
                }
                if (BLO) {
                    bf16x8 bl = *(const bf16x8*)(sm2 + OFF_BL + ((wc * NI + ni) * 64 + lane) * 8);
                    #pragma unroll
                    for (int mi = 0; mi < MI; ++mi)
                        acc[mi][ni] = __builtin_amdgcn_mfma_f32_16x16x32_bf16(ah[mi], bl, acc[mi][ni], 0, 0, 0);
                }
            }
        }
        __syncthreads();
    }

    for (int mi = 0; mi < MI; ++mi) {
        for (int i = 0; i < 4; ++i) {
            int row = m0 + wr * (BM / 2) + mi * 16 + lg * 4 + i;
            for (int ni = 0; ni < NI; ++ni) {
                int col = n0 + wc * (BN / 2) + ni * 16 + lr;
                float v = acc[mi][ni][i] * scale;
                if (bias) v += bias[col];
                if (EPI == 0) {
                    outF[(long)row * ldo + col + oOff] = v;
                } else if (EPI == 1) {
                    __hip_bfloat16 h, l;
                    split2(v, h, l);
                    outHi[(long)row * ldo + col + oOff] = h;
                    outLo[(long)row * ldo + col + oOff] = l;
                } else if (EPI == 2) {
                    // Q/K/V hi-only fragment-order scatter
                    int dirb = row >> 10, rloc = row & 1023;
                    int tq = col >> 8, within = col & 255;
                    int h4 = within >> 6, hd = within & 63;
                    __hip_bfloat16 hh = __float2bfloat16(v);
                    if (tq == 2) {
                        int w2 = rloc >> 8, mloc = rloc & 255;
                        int lane2 = ((mloc & 31) >> 3) * 16 + (hd & 15);
                        long idx = ((((long)(dirb*4+h4)*4 + w2)*8 + (mloc>>5))*4 + (hd>>4))*512 + lane2*8 + (mloc&7);
                        outHi2[idx] = hh;
                    } else {
                        int lane2 = ((hd & 31) >> 3) * 16 + (rloc & 15);
                        long idx = (((long)(dirb*4+h4)*64 + (rloc>>4))*2 + (hd>>5))*512 + lane2*8 + (hd&7);
                        if (tq == 0) outHi[idx] = hh;
                        else         outHi3[idx] = hh;
                    }
                } else if (EPI == 3) { // fused residual (descF) + cat planes cols 0..255
                    long i256 = (long)row * 256 + col;
                    v += outF[i256];
                    outF[i256] = v;
                    __hip_bfloat16 h, l;
                    split2(v, h, l);
                    outHi[(long)row * 512 + col] = h;
                    outLo[(long)row * 512 + col] = l;
                } else { // EPI==4: bf16 hi only
                    outHi[(long)row * ldo + col + oOff] = __float2bfloat16(v);
                }
            }
        }
    }
}

// =======================================================================
// Fully fused attention. Q,K,V hi-only. 16 q-rows/block. Fragment-order loads.
// =======================================================================
__global__ __launch_bounds__(256) void attn_fused(
    const __hip_bfloat16* __restrict__ qFh,
    const __hip_bfloat16* __restrict__ kFh, const __hip_bfloat16* __restrict__ vFh,
    __hip_bfloat16* __restrict__ catHi)
{
    __shared__ short pLds[4 * 16 * 256];   // 32KB; reused as f32 partials
    __shared__ float redm[4][16], reds[4][16];
    const int y = blockIdx.y;
    const int dir = y >> 3, b = (y >> 2) & 1, h = y & 3;
    const int q0 = blockIdx.x * 16;
    const int t = threadIdx.x, lane = t & 63, w = t >> 6;
    const int lr = lane & 15, lg = lane >> 4;
    const int dbQ = dir * 2 + b;
    const int srcdb = (1 - dir) * 2 + b;
    const short* qh = (const short*)qFh;
    const short* kh = (const short*)kFh;
    const short* vh = (const short*)vFh;

    const long qbase = (((long)(dbQ * 4 + h)) * 64 + (q0 >> 4)) * 2;
    bf16x8 ah[2];
    #pragma unroll
    for (int kc = 0; kc < 2; ++kc)
        ah[kc] = *(const bf16x8*)(qh + (qbase + kc) * 512 + lane * 8);

    f32x4 acc[16];
    #pragma unroll
    for (int ni = 0; ni < 16; ++ni) acc[ni] = f32x4{0.f, 0.f, 0.f, 0.f};

    const long kbase0 = (((long)(srcdb * 4 + h)) * 64 + w * 16) * 2;
    #pragma unroll
    for (int ni = 0; ni < 16; ++ni) {
        long kb = (kbase0 + ni * 2) * 512 + lane * 8;
        bf16x8 bh0 = *(const bf16x8*)(kh + kb);
        bf16x8 bh1 = *(const bf16x8*)(kh + kb + 512);
        acc[ni] = __builtin_amdgcn_mfma_f32_16x16x32_bf16(ah[0], bh0, acc[ni], 0, 0, 0);
        acc[ni] = __builtin_amdgcn_mfma_f32_16x16x32_bf16(ah[1], bh1, acc[ni], 0, 0, 0);
    }

    float mx[4] = {-1e30f, -1e30f, -1e30f, -1e30f};
    #pragma unroll
    for (int ni = 0; ni < 16; ++ni)
        #pragma unroll
        for (int i = 0; i < 4; ++i) {
            float v = acc[ni][i] * 0.125f;
            acc[ni][i] = v;
            mx[i] = fmaxf(mx[i], v);
        }
    #pragma unroll
    for (int off = 1; off < 16; off <<= 1)
        #pragma unroll
        for (int i = 0; i < 4; ++i) mx[i] = fmaxf(mx[i], __shfl_xor(mx[i], off));
    if (lr == 0)
        #pragma unroll
        for (int i = 0; i < 4; ++i) redm[w][lg * 4 + i] = mx[i];
    __syncthreads();
    float Mv[4];
    #pragma unroll
    for (int i = 0; i < 4; ++i)
        Mv[i] = fmaxf(fmaxf(redm[0][lg*4+i], redm[1][lg*4+i]),
                      fmaxf(redm[2][lg*4+i], redm[3][lg*4+i]));
    float sm[4] = {0.f, 0.f, 0.f, 0.f};
    #pragma unroll
    for (int ni = 0; ni < 16; ++ni)
        #pragma unroll
        for (int i = 0; i < 4; ++i) {
            float e = __expf(acc[ni][i] - Mv[i]);
            acc[ni][i] = e;
            sm[i] += e;
        }
    #pragma unroll
    for (int off = 1; off < 16; off <<= 1)
        #pragma unroll
        for (int i = 0; i < 4; ++i) sm[i] += __shfl_xor(sm[i], off);
    if (lr == 0)
        #pragma unroll
        for (int i = 0; i < 4; ++i) reds[w][lg * 4 + i] = sm[i];
    __syncthreads();
    float inv[4];
    #pragma unroll
    for (int i = 0; i < 4; ++i)
        inv[i] = 1.f / (reds[0][lg*4+i] + reds[1][lg*4+i] + reds[2][lg*4+i] + reds[3][lg*4+i]);

    char* pB = (char*)pLds + w * 8192;
    #pragma unroll
    for (int ni = 0; ni < 16; ++ni)
        #pragma unroll
        for (int i = 0; i < 4; ++i) {
            int q = lg * 4 + i, m = ni * 16 + lr;
            int byte = (q * 512 + m * 2) ^ ((q & 7) << 4);
            *(short*)(pB + byte) = (short)__bfloat16_as_ushort(__float2bfloat16(acc[ni][i] * inv[i]));
        }
    __syncthreads();

    f32x4 acc2[4];
    #pragma unroll
    for (int bi = 0; bi < 4; ++bi) acc2[bi] = f32x4{0.f, 0.f, 0.f, 0.f};
    const long vbase0 = (((long)(srcdb * 4 + h)) * 4 + w) * 8;
    #pragma unroll
    for (int km = 0; km < 8; ++km) {
        int rb = (lr * 512 + km * 64 + lg * 16) ^ ((lr & 7) << 4);
        bf16x8 pa = *(const bf16x8*)(pB + rb);
        #pragma unroll
        for (int bi = 0; bi < 4; ++bi) {
            long vr = ((vbase0 + km) * 4 + bi) * 512 + lane * 8;
            bf16x8 vhf = *(const bf16x8*)(vh + vr);
            acc2[bi] = __builtin_amdgcn_mfma_f32_16x16x32_bf16(pa, vhf, acc2[bi], 0, 0, 0);
        }
    }
    __syncthreads();
    float* pr = (float*)pLds;
    #pragma unroll
    for (int bi = 0; bi < 4; ++bi)
        #pragma unroll
        for (int i = 0; i < 4; ++i)
            pr[w * 1024 + (lg * 4 + i) * 64 + bi * 16 + lr] = acc2[bi][i];
    __syncthreads();
    #pragma unroll
    for (int k = 0; k < 4; ++k) {
        int e = t + k * 256;
        float v = pr[e] + pr[1024 + e] + pr[2048 + e] + pr[3072 + e];
        int q = e >> 6, d = e & 63;
        long a = ((long)dbQ * 1024 + q0 + q) * 512 + 256 + h * 64 + d;
        catHi[a] = __float2bfloat16(v);
    }
}

// ---------------- LN(channel,ddof=1,eps-on-std)+ReLU; wave-per-row; bf16 in-place ----------------
__global__ __launch_bounds__(256) void ln_relu_w(
    __hip_bfloat16* __restrict__ y, const float* __restrict__ g, const float* __restrict__ be)
{
    const int t = threadIdx.x, lane = t & 63, w = t >> 6;
    const long row = (long)blockIdx.x * 4 + w;
    short* src = (short*)y + row * 512;
    bf16x8 r = *(const bf16x8*)(src + lane * 8);
    float xv[8];
    #pragma unroll
    for (int k = 0; k < 8; ++k) xv[k] = bf2f(r[k]);
    float s = 0.f, q = 0.f;
    #pragma unroll
    for (int k = 0; k < 8; ++k) { s += xv[k]; q += xv[k] * xv[k]; }
    #pragma unroll
    for (int off = 1; off < 64; off <<= 1) {
        s += __shfl_xor(s, off);
        q += __shfl_xor(q, off);
    }
    float mean = s / 512.f;
    float var = fmaxf((q - 512.f * mean * mean) / 511.f, 0.f);
    float rstd = 1.f / (sqrtf(var) + LN_EPS);
    float4 g0 = ((const float4*)g)[lane * 2], g1 = ((const float4*)g)[lane * 2 + 1];
    float4 b0 = ((const float4*)be)[lane * 2], b1 = ((const float4*)be)[lane * 2 + 1];
    float gv[8] = {g0.x, g0.y, g0.z, g0.w, g1.x, g1.y, g1.z, g1.w};
    float bv[8] = {b0.x, b0.y, b0.z, b0.w, b1.x, b1.y, b1.z, b1.w};
    bf16x8 outv;
    #pragma unroll
    for (int k = 0; k < 8; ++k) {
        float o = fmaxf(gv[k] * (xv[k] - mean) * rstd + bv[k], 0.f);
        outv[k] = (short)__bfloat16_as_ushort(__float2bfloat16(o));
    }
    *(bf16x8*)(src + lane * 8) = outv;
}

// ---------------- weight converts ----------------
__global__ __launch_bounds__(256) void wconv_hi(
    const float* __restrict__ w, __hip_bfloat16* __restrict__ hi, long total)
{
    long i = (long)blockIdx.x * 256 + threadIdx.x;
    if (i >= total) return;
    hi[i] = __float2bfloat16(w[i]);
}

__global__ __launch_bounds__(256) void wconv_proj(
    const float* __restrict__ w, __hip_bfloat16* __restrict__ hi)
{
    long i = (long)blockIdx.x * 256 + threadIdx.x;
    if (i >= 9L * 768 * 256) return;
    long l9 = i / (768 * 256);
    int rem = (int)(i % (768 * 256));
    int op = rem / 256, c = rem % 256;
    int tq = op / 256, within = op % 256;
    int h = within / 64, hd = within % 64;
    int o = tq * 256 + hd * 4 + h;
    hi[i] = __float2bfloat16(w[(l9 * 768 + o) * 256 + c]);
}

__global__ void wconv_proj_bias(const float* __restrict__ b, float* __restrict__ bp)
{
    int i = blockIdx.x * 256 + threadIdx.x;
    if (i >= 9 * 768) return;
    int l9 = i / 768, op = i % 768;
    int tq = op / 256, within = op % 256;
    int h = within / 64, hd = within % 64;
    bp[i] = b[(l9 * 3 + tq) * 256 + hd * 4 + h];
}

// WmT planes: [l][c=h*64+hd][j] = Wm[l][j][hd*4+h]  (hi/lo: B operand of fold GEMM)
__global__ __launch_bounds__(256) void wconv_mergeT(
    const float* __restrict__ w, __hip_bfloat16* __restrict__ hi, __hip_bfloat16* __restrict__ lo)
{
    long i = (long)blockIdx.x * 256 + threadIdx.x;
    if (i >= 9L * 256 * 256) return;
    long l9 = i / (256 * 256);
    int rem = (int)(i % (256 * 256));
    int c = rem / 256, j = rem % 256;
    int h = c / 64, hd = c % 64;
    float v = w[(l9 * 256 + j) * 256 + (hd * 4 + h)];
    __hip_bfloat16 hh, ll; split2(v, hh, ll);
    hi[i] = hh; lo[i] = ll;
}

// mlp1 W split: cols 0..255 -> m1cHi[..512-wide]; cols 256..511 -> m1b hi/lo [..256-wide]
__global__ __launch_bounds__(256) void wconv_m1(
    const float* __restrict__ w,
    __hip_bfloat16* __restrict__ m1cHi,
    __hip_bfloat16* __restrict__ m1bHi, __hip_bfloat16* __restrict__ m1bLo)
{
    long i = (long)blockIdx.x * 256 + threadIdx.x;
    if (i >= 9L * 512 * 512) return;
    long lo9 = i / 512;
    int c = (int)(i % 512);
    if (c < 256) {
        m1cHi[lo9 * 512 + c] = __float2bfloat16(w[i]);
    } else {
        __hip_bfloat16 hh, ll; split2(w[i], hh, ll);
        m1bHi[lo9 * 256 + c - 256] = hh; m1bLo[lo9 * 256 + c - 256] = ll;
    }
}

// b1c[l*512+o] = b1[l][o] + sum_j W1[l][o][256+j]*bm[l][j]
__global__ __launch_bounds__(64) void bias_fold(
    const float* __restrict__ w1, const float* __restrict__ b1,
    const float* __restrict__ bm, float* __restrict__ out)
{
    int og = blockIdx.x;
    int l = og >> 9, o = og & 511;
    int t = threadIdx.x;
    float s = 0.f;
    for (int j = t; j < 256; j += 64)
        s += w1[((long)l * 512 + o) * 512 + 256 + j] * bm[l * 256 + j];
    for (int off = 32; off > 0; off >>= 1) s += __shfl_down(s, off);
    if (t == 0) out[og] = b1[(long)l * 512 + o] + s;
}

// ---------------- Sinkhorn pieces (padded LDZ=1028 layout) ----------------
__global__ void bins_fill(float* __restrict__ Z, const float* __restrict__ alpha_p)
{
    float alpha = alpha_p[0];
    int idx = blockIdx.x * 256 + threadIdx.x;
    int b = blockIdx.y;
    float* Zb = Z + (long)b * NP1c * LDZ;
    if (idx < NP1c) Zb[(long)1024 * LDZ + idx] = alpha;
    else { int i = idx - NP1c; if (i < 1024) Zb[(long)i * LDZ + 1024] = alpha; }
}

__global__ void transpose_np1(const float* __restrict__ Z, float* __restrict__ ZT)
{
    __shared__ float tile[32][33];
    int b = blockIdx.z;
    int i0 = blockIdx.y * 32, j0 = blockIdx.x * 32;
    int tx = threadIdx.x, ty = threadIdx.y;
    const float* Zb = Z + (long)b * NP1c * LDZ;
    float* Tb = ZT + (long)b * NP1c * LDZ;
    for (int ii = ty; ii < 32; ii += 8) {
        int i = i0 + ii, j = j0 + tx;
        if (i < NP1c && j < NP1c) tile[ii][tx] = Zb[(long)i * LDZ + j];
    }
    __syncthreads();
    for (int jj = ty; jj < 32; jj += 8) {
        int j = j0 + jj, i = i0 + tx;
        if (j < NP1c && i < NP1c) Tb[(long)j * LDZ + i] = tile[tx][jj];
    }
}

__global__ void zero_vec2(float* __restrict__ a, float* __restrict__ b, int n)
{
    int i = blockIdx.x * 256 + threadIdx.x;
    if (i < n) { a[i] = 0.f; b[i] = 0.f; }
}

// wave-per-row LSE: out[b][i] = lmu(i) - LSE_j( M[b][i][j] + addv[b][j] )
__global__ __launch_bounds__(256) void sinkhorn_lse(
    const float* __restrict__ M, const float* __restrict__ addv, float* __restrict__ outv)
{
    const int t = threadIdx.x, lane = t & 63, w = t >> 6;
    long rowid = (long)blockIdx.x * 4 + w;
    if (rowid >= 2 * NP1c) return;        // wave-uniform exit
    int b = rowid >= NP1c ? 1 : 0;
    int i = (int)(rowid - (long)b * NP1c);
    const float* row = M + ((long)b * NP1c + i) * LDZ;
    const float* av = addv + (long)b * LDV;
    float m = -1e30f, s = 0.f;
    #pragma unroll
    for (int k = 0; k < 4; ++k) {
        float4 x = ((const float4*)row)[lane * 4 + k];
        float4 a = ((const float4*)av)[lane * 4 + k];
        float u0 = x.x + a.x, u1 = x.y + a.y, u2 = x.z + a.z, u3 = x.w + a.w;
        float mk = fmaxf(fmaxf(u0, u1), fmaxf(u2, u3));
        float sk = __expf(u0 - mk) + __expf(u1 - mk) + __expf(u2 - mk) + __expf(u3 - mk);
        if (mk > m) { s = s * __expf(m - mk) + sk; m = mk; }
        else        { s += sk * __expf(mk - m); }
    }
    if (lane == 0) {
        float v4 = row[1024] + av[1024];
        if (v4 > m) { s = s * __expf(m - v4) + 1.f; m = v4; }
        else        { s += __expf(v4 - m); }
    }
    #pragma unroll
    for (int off = 1; off < 64; off <<= 1) {
        float m2 = __shfl_xor(m, off);
        float s2 = __shfl_xor(s, off);
        float mm = fmaxf(m, m2);
        s = s * __expf(m - mm) + s2 * __expf(m2 - mm);
        m = mm;
    }
    if (lane == 0) {
        float lse = m + __logf(s);
        float lmu = (i < 1024) ? NORMV : (LOGNV + NORMV);
        outv[(long)b * LDV + i] = lmu - lse;
    }
}

__global__ __launch_bounds__(256) void final_out_k(
    const float* __restrict__ Z, const float* __restrict__ u,
    const float* __restrict__ v, float* __restrict__ outp)
{
    const int i = blockIdx.x, b = blockIdx.y, t = threadIdx.x;
    const float* row = Z + ((long)b * NP1c + i) * LDZ;
    float* orow = outp + ((long)b * NP1c + i) * NP1c;
    float ui = u[(long)b * LDV + i];
    for (int j = t; j < NP1c; j += 256)
        orow[j] = row[j] + ui + v[(long)b * LDV + j] - NORMV;
}

// =======================================================================
extern "C" void kernel_launch(void* const* d_in, const int* in_sizes, int n_in,
                              void* d_out, int out_size, void* d_ws, size_t ws_size,
                              hipStream_t stream)
{
    (void)in_sizes; (void)n_in; (void)out_size; (void)ws_size;
    const float* kpts0   = (const float*)d_in[0];
    const float* kpts1   = (const float*)d_in[1];
    const float* scores0 = (const float*)d_in[2];
    const float* scores1 = (const float*)d_in[3];
    const float* desc0   = (const float*)d_in[4];
    const float* desc1   = (const float*)d_in[5];
    const float* kw0 = (const float*)d_in[6];  const float* kb0 = (const float*)d_in[7];
    const float* kg0 = (const float*)d_in[8];  const float* ke0 = (const float*)d_in[9];
    const float* kw1 = (const float*)d_in[10]; const float* kb1 = (const float*)d_in[11];
    const float* kg1 = (const float*)d_in[12]; const float* ke1 = (const float*)d_in[13];
    const float* kw2 = (const float*)d_in[14]; const float* kb2 = (const float*)d_in[15];
    const float* kg2 = (const float*)d_in[16]; const float* ke2 = (const float*)d_in[17];
    const float* kw3 = (const float*)d_in[18]; const float* kb3 = (const float*)d_in[19];
    const float* gnn_proj_w  = (const float*)d_in[20];
    const float* gnn_proj_b  = (const float*)d_in[21];
    const float* gnn_merge_w = (const float*)d_in[22];
    const float* gnn_merge_b = (const float*)d_in[23];
    const float* gnn_mlp1_w  = (const float*)d_in[24];
    const float* gnn_mlp1_b  = (const float*)d_in[25];
    const float* gnn_ln_g    = (const float*)d_in[26];
    const float* gnn_ln_b    = (const float*)d_in[27];
    const float* gnn_mlp2_w  = (const float*)d_in[28];
    const float* gnn_mlp2_b  = (const float*)d_in[29];
    const float* final_w     = (const float*)d_in[30];
    const float* final_b     = (const float*)d_in[31];
    const float* bin_score   = (const float*)d_in[32];

    char* wsb = (char*)d_ws;
    size_t off = 0;
    auto alloc = [&](size_t bytes) -> void* {
        void* p = wsb + off;
        off = (off + bytes + 255) & ~(size_t)255;
        return p;
    };
    typedef __hip_bfloat16 bf;
    const long ROWS = 4L * Nc;
    // fp32
    float* descF  = (float*)alloc(ROWS * 256 * 4);
    float* descT  = (float*)alloc(ROWS * 256 * 4);
    float* Zm     = (float*)alloc((long)Bc * NP1c * LDZ * 4);
    float* ZT     = (float*)alloc((long)Bc * NP1c * LDZ * 4);
    float* uvec   = (float*)alloc(Bc * LDV * 4);
    float* vvec   = (float*)alloc(Bc * LDV * 4);
    float* projBp = (float*)alloc(9L * 768 * 4);
    float* b1c    = (float*)alloc(9L * 512 * 4);
    float* kw1T   = (float*)alloc(32L * 64 * 4);
    float* kw2T   = (float*)alloc(64L * 128 * 4);
    float* kw3T   = (float*)alloc(128L * 256 * 4);
    // activation planes
    bf* catHi = (bf*)alloc(ROWS * 512 * 2);  bf* catLo = (bf*)alloc(ROWS * 512 * 2);
    bf* qFh = (bf*)alloc(1048576 * 2);
    bf* kFh = (bf*)alloc(1048576 * 2);
    bf* vFh = (bf*)alloc(1048576 * 2);
    bf* ybHi  = (bf*)alloc(ROWS * 512 * 2);
    bf* mdHi  = (bf*)alloc(ROWS * 256 * 2);  bf* mdLo  = (bf*)alloc(ROWS * 256 * 2);
    // weight planes
    bf* projHi = (bf*)alloc(9L*768*256*2);
    bf* mrgTHi = (bf*)alloc(9L*256*256*2);   bf* mrgTLo = (bf*)alloc(9L*256*256*2);
    bf* m1bHi  = (bf*)alloc(9L*512*256*2);   bf* m1bLo  = (bf*)alloc(9L*512*256*2);
    bf* m1cHi  = (bf*)alloc(9L*512*512*2);
    bf* m2Hi   = (bf*)alloc(9L*256*512*2);
    bf* finHi  = (bf*)alloc(256L*256*2);

    // ---- weight prep ----
    wconv_proj<<<dim3((9*768*256+255)/256), 256, 0, stream>>>(gnn_proj_w, projHi);
    wconv_proj_bias<<<dim3(27), 256, 0, stream>>>(gnn_proj_b, projBp);
    wconv_mergeT<<<dim3((9*256*256+255)/256), 256, 0, stream>>>(gnn_merge_w, mrgTHi, mrgTLo);
    wconv_m1<<<dim3((int)((9L*512*512+255)/256)), 256, 0, stream>>>(gnn_mlp1_w, m1cHi, m1bHi, m1bLo);
    wconv_hi<<<dim3((9*256*512+255)/256), 256, 0, stream>>>(gnn_mlp2_w, m2Hi, 9L*256*512);
    wconv_hi<<<dim3((256*256+255)/256), 256, 0, stream>>>(final_w, finHi, 256L*256);
    bias_fold<<<dim3(9*512), 64, 0, stream>>>(gnn_mlp1_w, gnn_mlp1_b, gnn_merge_b, b1c);
    transposeW<<<dim3((64*32+255)/256), 256, 0, stream>>>(kw1, kw1T, 64, 32);
    transposeW<<<dim3((128*64+255)/256), 256, 0, stream>>>(kw2, kw2T, 128, 64);
    transposeW<<<dim3((256*128+255)/256), 256, 0, stream>>>(kw3, kw3T, 256, 128);
    // combined mlp1 cols 256..511 = W1b x WmT^T per layer (hi out; inputs hi/lo)
    mfma_nt<128,128,4,1,1,2><<<dim3(2,4,9), 256, 0, stream>>>(
        (const short*)m1bHi, (const short*)m1bLo, 256,
        (const short*)mrgTHi, (const short*)mrgTLo, 256,
        256, 1.f, nullptr,
        nullptr, m1cHi + 256, nullptr, nullptr, nullptr, 512,
        512L*256, 256L*256, 512L*512);

    // ---- desc transpose + keypoint encoder -> descF + cat planes cols 0..255 ----
    transpose_desc<<<dim3(32,8,4), dim3(32,8), 0, stream>>>(desc0, desc1, descT);
    kenc_kernel<<<dim3(Nc, 4), 256, 0, stream>>>(
        kpts0, kpts1, scores0, scores1, descT, descF, catHi, catLo,
        kw0, kb0, kg0, ke0, kw1T, kb1, kg1, ke1, kw2T, kb2, kg2, ke2, kw3T, kb3);

    // ---- GNN layers ----
    for (int l = 0; l < 9; ++l) {
        // 1) qkv GEMM (A hi, W hi, BKC=4) -> Q/K/V hi fragment-order
        mfma_nt<64,64,2,0,0,4><<<dim3(12,64,1), 256, 0, stream>>>(
            (const short*)catHi, nullptr, 512,
            (const short*)(projHi + (long)l*768*256), nullptr, 256,
            256, 1.f, projBp + (long)l*768,
            nullptr, qFh, nullptr, vFh, kFh, 0,
            0, 0, 0);
        // 2) fused attention (16 q-rows/block) -> catbuf hi cols 256..511
        attn_fused<<<dim3(64, 16), 256, 0, stream>>>(qFh, kFh, vFh, catHi);
        // 3) mlp1 (A hi, W hi, BKC=4) -> ybHi bf16 directly
        mfma_nt<64,64,4,0,0,4><<<dim3(8,64,1), 256, 0, stream>>>(
            (const short*)catHi, nullptr, 512,
            (const short*)(m1cHi + (long)l*512*512), nullptr, 512,
            512, 1.f, b1c + (long)l*512,
            nullptr, ybHi, nullptr, nullptr, nullptr, 512,
            0, 0, 0);
        // 4) LN+ReLU (wave-per-row, bf16 in-place)
        ln_relu_w<<<dim3(1024), 256, 0, stream>>>(
            ybHi, gnn_ln_g + (long)l*512, gnn_ln_b + (long)l*512);
        // 5) mlp2 (A hi, W hi, BKC=4) fused residual -> descF + cat hi/lo cols 0..255
        mfma_nt<64,64,3,0,0,4><<<dim3(4,64,1), 256, 0, stream>>>(
            (const short*)ybHi, nullptr, 512,
            (const short*)(m2Hi + (long)l*256*512), nullptr, 512,
            512, 1.f, gnn_mlp2_b + (long)l*256,
            descF, catHi, catLo, nullptr, nullptr, 0,
            0, 0, 0);
    }

    // ---- final projection (A hi/lo, W hi, BKC=4) -> mdesc planes ----
    mfma_nt<64,64,1,0,1,4><<<dim3(4,64,1), 256, 0, stream>>>(
        (const short*)catHi, (const short*)catLo, 512,
        (const short*)finHi, nullptr, 256,
        256, 1.f, final_b,
        nullptr, mdHi, mdLo, nullptr, nullptr, 256,
        0, 0, 0);
    // ---- score matrix into Z (activation x activation: full hi/lo; BKC=4) ----
    mfma_nt<64,64,0,1,1,4><<<dim3(16,16,2), 256, 0, stream>>>(
        (const short*)mdHi, (const short*)mdLo, 256,
        (const short*)mdHi + 2048L*256, (const short*)mdLo + 2048L*256, 256,
        256, 1.f/16.f, nullptr,
        Zm, nullptr, nullptr, nullptr, nullptr, LDZ,
        1024L*256, 1024L*256, (long)NP1c*LDZ);
    bins_fill<<<dim3(9,2), 256, 0, stream>>>(Zm, bin_score);

    // ---- Sinkhorn (log-space), 20 iterations (wave-per-row LSE) ----
    transpose_np1<<<dim3(33,33,2), dim3(32,8), 0, stream>>>(Zm, ZT);
    zero_vec2<<<dim3((2*LDV+255)/256), 256, 0, stream>>>(uvec, vvec, Bc * LDV);
    for (int it = 0; it < 20; ++it) {
        sinkhorn_lse<<<dim3(513), 256, 0, stream>>>(Zm, vvec, uvec);
        sinkhorn_lse<<<dim3(513), 256, 0, stream>>>(ZT, uvec, vvec);
    }
    final_out_k<<<dim3(NP1c, Bc), 256, 0, stream>>>(Zm, uvec, vvec, (float*)d_out);
}